// Round 5
// baseline (349.678 us; speedup 1.0000x reference)
//
#include <hip/hip_runtime.h>
#include <math.h>

#define B_ 32
#define C_ 3
#define H_ 512
#define W_ 512
#define NOUT 64
#define FAN (C_*H_*W_)          // 786432

// locnet: one block = 1024-wide k-chunk x all 32 batches; W chunk in LDS.
#define LCHUNKS 768
#define LCE 1024                // k-elements per chunk

// ws layout (bytes): [0,1024) p-accumulators (float), then 4 bf16 arrays
#define FXH_OFF 1024
#define ARR_ELEMS (B_*NOUT*W_)          // 1048576 ushorts = 2 MB each

typedef __bf16 bf16x8 __attribute__((ext_vector_type(8)));
typedef float f32x4 __attribute__((ext_vector_type(4)));

__device__ __forceinline__ unsigned short f2bf(float f) {
    unsigned int u = __float_as_uint(f);
    u = (u + 0x7FFFu + ((u >> 16) & 1u)) >> 16;
    return (unsigned short)u;
}
__device__ __forceinline__ float bf2f(unsigned short h) {
    return __uint_as_float(((unsigned int)h) << 16);
}
// 8 floats -> hi/lo bf16x8
__device__ __forceinline__ void cvt_hilo(const float* x, bf16x8* hi, bf16x8* lo) {
    union { unsigned int u[4]; bf16x8 v; } H, L;
    #pragma unroll
    for (int i = 0; i < 4; i++) {
        unsigned short h0 = f2bf(x[2*i]),  h1 = f2bf(x[2*i+1]);
        H.u[i] = (unsigned int)h0 | ((unsigned int)h1 << 16);
        unsigned short l0 = f2bf(x[2*i]   - bf2f(h0));
        unsigned short l1 = f2bf(x[2*i+1] - bf2f(h1));
        L.u[i] = (unsigned int)l0 | ((unsigned int)l1 << 16);
    }
    *hi = H.v; *lo = L.v;
}

// ---------------- kernel 1: p[b,j] = sum_i X[b,i] * W_loc[i,j] ----------------
// Block: k-chunk of LCE, all 32 batches. W chunk staged once in LDS (20 KB).
// Thread (bb = t>>3, j8 = t&7): acc[5] only -> no spill.
__global__ __launch_bounds__(256) void k_locnet(const float* __restrict__ X,
                                                const float* __restrict__ Wl,
                                                float* __restrict__ ws) {
    const int chunk = blockIdx.x;        // 0..767
    const int t = threadIdx.x;
    const size_t kbase = (size_t)chunk * LCE;

    __shared__ __align__(16) float Wlds[LCE * 5];   // 20 KB
    {
        const float4* Wg = (const float4*)(Wl + kbase * 5);  // 20KB-multiple offset, aligned
        #pragma unroll
        for (int i = 0; i < 5; i++)
            *(float4*)&Wlds[(t + 256 * i) * 4] = Wg[t + 256 * i];
    }
    __syncthreads();

    const int bb = t >> 3;   // 0..31
    const int j8 = t & 7;    // 0..7
    const float* Xr = X + (size_t)bb * FAN + kbase;

    float acc[5] = {};
    #pragma unroll 8
    for (int i = 0; i < 32; i++) {
        const int k0 = (j8 + 8 * i) * 4;
        float4 x = *(const float4*)(Xr + k0);
        const float* wr = &Wlds[k0 * 5];
        float xa[4] = {x.x, x.y, x.z, x.w};
        #pragma unroll
        for (int e = 0; e < 4; e++)
            #pragma unroll
            for (int jj = 0; jj < 5; jj++)
                acc[jj] += xa[e] * wr[e * 5 + jj];
    }

    // reduce over the 8 k-lanes of this batch (within-wave)
    #pragma unroll
    for (int off = 1; off < 8; off <<= 1)
        #pragma unroll
        for (int jj = 0; jj < 5; jj++)
            acc[jj] += __shfl_xor(acc[jj], off);

    if (j8 == 0) {
        #pragma unroll
        for (int jj = 0; jj < 5; jj++)
            atomicAdd(&ws[bb * 5 + jj], acc[jj]);
    }
}

// ---------------- kernel 2: filters -> bf16 hi/lo in ws ----------------
__global__ __launch_bounds__(256) void k_filters(const float* __restrict__ bl,
                                                 void* __restrict__ wsv) {
    const int n = blockIdx.x;      // 0..63
    const int b = blockIdx.y;      // 0..31
    const int which = blockIdx.z;  // 0: Fx, 1: Fy
    const int t = threadIdx.x;

    const float* pw = (const float*)wsv;
    unsigned short* arrh = (unsigned short*)((char*)wsv + FXH_OFF) + (size_t)which * 2 * ARR_ELEMS;
    unsigned short* arrl = arrh + ARR_ELEMS;

    const float p0 = pw[b * 5 + 0] + bl[0];
    const float p1 = pw[b * 5 + 1] + bl[1];
    const float p2 = pw[b * 5 + 2] + bl[2];
    const float p3 = pw[b * 5 + 3] + bl[3];

    const float g = (which == 0) ? 32.f * (p0 + 1.f) : 32.f * (p1 + 1.f);
    const float inv2s = 0.5f / expf(p2);
    const float delta = expf(p3) * (511.0f / 63.0f);
    const float mean = g + delta * ((float)n - 32.5f);

    float d0 = (float)t - mean;
    float f0 = expf(-d0 * d0 * inv2s);
    float d1 = (float)(t + 256) - mean;
    float f1 = expf(-d1 * d1 * inv2s);

    float s = f0 + f1;
    #pragma unroll
    for (int off = 32; off > 0; off >>= 1) s += __shfl_down(s, off);
    __shared__ float sred[4];
    __shared__ float stot;
    const int wave = t >> 6, lane = t & 63;
    if (lane == 0) sred[wave] = s;
    __syncthreads();
    if (t == 0) stot = sred[0] + sred[1] + sred[2] + sred[3] + 1e-4f;
    __syncthreads();
    const float scale = 1.0f / stot;

    const size_t o = ((size_t)b * NOUT + n) * W_;
    float v0 = f0 * scale, v1 = f1 * scale;
    unsigned short h0 = f2bf(v0), h1 = f2bf(v1);
    arrh[o + t] = h0;
    arrh[o + t + 256] = h1;
    arrl[o + t] = f2bf(v0 - bf2f(h0));
    arrl[o + t + 256] = f2bf(v1 - bf2f(h1));
}

// ---------------- kernel 3: MFMA glimpse, direct-fragment global loads ----------------
#define GP 72   // ushort pitch for G^T rows in LDS

__global__ __launch_bounds__(256) void k_glimpse(const float* __restrict__ X,
                                                 const float* __restrict__ bl,
                                                 const void* __restrict__ wsv,
                                                 float* __restrict__ out) {
    const int hc = blockIdx.x;   // 0..7
    const int bc = blockIdx.y;   // 0..95
    const int b = bc / 3;
    const int t = threadIdx.x;
    const int lane = t & 63;
    const int wv = t >> 6;       // 0..3
    const int l15 = lane & 15;
    const int quad = lane >> 4;  // 0..3
    const int hbase = hc * 64;

    const float* pw = (const float*)wsv;
    const unsigned short* fxh = (const unsigned short*)((const char*)wsv + FXH_OFF) + (size_t)b * NOUT * W_;
    const unsigned short* fxl = fxh + ARR_ELEMS;
    const unsigned short* fyh = fxh + 2 * ARR_ELEMS;
    const unsigned short* fyl = fxh + 3 * ARR_ELEMS;

    __shared__ __align__(16) unsigned short Gh[64 * GP];
    __shared__ __align__(16) unsigned short Gl[64 * GP];

    const float* Xp = X + (size_t)bc * (H_ * W_);

    // ---- GEMM1: barrier-free, frags straight from global ----
    f32x4 ahh[4] = {}, axl[4] = {};
    const size_t arow = (size_t)(hbase + 16 * wv + l15) * W_;
    #pragma unroll 4
    for (int ks = 0; ks < 16; ks++) {
        const int ko = ks * 32 + quad * 8;
        float xa[8];
        *(float4*)&xa[0] = *(const float4*)(Xp + arow + ko);
        *(float4*)&xa[4] = *(const float4*)(Xp + arow + ko + 4);
        bf16x8 ah, al;
        cvt_hilo(xa, &ah, &al);
        #pragma unroll
        for (int mt = 0; mt < 4; mt++) {
            const int fo = (16 * mt + l15) * W_ + ko;
            bf16x8 bh  = *(const bf16x8*)&fxh[fo];
            bf16x8 bl2 = *(const bf16x8*)&fxl[fo];
            ahh[mt] = __builtin_amdgcn_mfma_f32_16x16x32_bf16(ah, bh,  ahh[mt], 0, 0, 0);
            axl[mt] = __builtin_amdgcn_mfma_f32_16x16x32_bf16(al, bh,  axl[mt], 0, 0, 0);
            axl[mt] = __builtin_amdgcn_mfma_f32_16x16x32_bf16(ah, bl2, axl[mt], 0, 0, 0);
        }
    }

    // G^T -> LDS hi/lo
    #pragma unroll
    for (int mt = 0; mt < 4; mt++) {
        unsigned short gh[4], gl[4];
        #pragma unroll
        for (int r = 0; r < 4; r++) {
            float g = ahh[mt][r] + axl[mt][r];
            gh[r] = f2bf(g);
            gl[r] = f2bf(g - bf2f(gh[r]));
        }
        int o = (16 * mt + l15) * GP + 16 * wv + quad * 4;
        *(uint2*)&Gh[o] = make_uint2((unsigned int)gh[0] | ((unsigned int)gh[1] << 16),
                                     (unsigned int)gh[2] | ((unsigned int)gh[3] << 16));
        *(uint2*)&Gl[o] = make_uint2((unsigned int)gl[0] | ((unsigned int)gl[1] << 16),
                                     (unsigned int)gl[2] | ((unsigned int)gl[3] << 16));
    }
    __syncthreads();

    // ---- GEMM2: P[n][m] = sum_h Fy[n][hbase+h] * G[h][m] ----
    f32x4 ph[4] = {}, px[4] = {};
    const size_t yrow = (size_t)(16 * wv + l15) * W_ + hbase;
    #pragma unroll
    for (int ks = 0; ks < 2; ks++) {
        const int ko = ks * 32 + quad * 8;
        bf16x8 yh = *(const bf16x8*)&fyh[yrow + ko];
        bf16x8 yl = *(const bf16x8*)&fyl[yrow + ko];
        #pragma unroll
        for (int mt = 0; mt < 4; mt++) {
            const int go = (16 * mt + l15) * GP + ko;
            bf16x8 gh = *(const bf16x8*)&Gh[go];
            bf16x8 gl = *(const bf16x8*)&Gl[go];
            ph[mt] = __builtin_amdgcn_mfma_f32_16x16x32_bf16(yh, gh, ph[mt], 0, 0, 0);
            px[mt] = __builtin_amdgcn_mfma_f32_16x16x32_bf16(yl, gh, px[mt], 0, 0, 0);
            px[mt] = __builtin_amdgcn_mfma_f32_16x16x32_bf16(yh, gl, px[mt], 0, 0, 0);
        }
    }

    const float gamma = expf(pw[b * 5 + 4] + bl[4]);
    float* outp = out + (size_t)bc * (NOUT * NOUT);
    #pragma unroll
    for (int mt = 0; mt < 4; mt++)
        #pragma unroll
        for (int r = 0; r < 4; r++) {
            int n = 16 * wv + quad * 4 + r;
            int m = 16 * mt + l15;
            atomicAdd(&outp[n * NOUT + m], gamma * (ph[mt][r] + px[mt][r]));
        }
}

extern "C" void kernel_launch(void* const* d_in, const int* in_sizes, int n_in,
                              void* d_out, int out_size, void* d_ws, size_t ws_size,
                              hipStream_t stream) {
    const float* X  = (const float*)d_in[0];
    const float* Wl = (const float*)d_in[1];
    const float* bl = (const float*)d_in[2];
    float* out = (float*)d_out;
    float* ws  = (float*)d_ws;

    hipMemsetAsync(ws, 0, 1024, stream);
    hipMemsetAsync(out, 0, (size_t)out_size * sizeof(float), stream);

    k_locnet<<<dim3(LCHUNKS), 256, 0, stream>>>(X, Wl, ws);
    k_filters<<<dim3(NOUT, B_, 2), 256, 0, stream>>>(bl, d_ws);
    k_glimpse<<<dim3(8, B_ * C_), 256, 0, stream>>>(X, bl, d_ws, out);
}

// Round 7
// 238.452 us; speedup vs baseline: 1.4665x; 1.4665x over previous
//
#include <hip/hip_runtime.h>
#include <math.h>

#define B_ 32
#define C_ 3
#define H_ 512
#define W_ 512
#define NOUT 64
#define FAN (C_*H_*W_)          // 786432

// locnet: one block = 1024-wide k-chunk x all 32 batches; W chunk in LDS.
#define LCHUNKS 768
#define LCE 1024                // k-elements per chunk

// ws layout (bytes) — total usage capped at 8,389,632 B (rounds 1-5 proven):
//   [0, 1024)            final p[32][5] (written by k_reduce)
//   [1024, 1024+8MB)     4 bf16 filter arrays (hi/lo x Fx/Fy), written by k_filters
//   partials OVERLAY the filter region at FXH_OFF: produced by k_locnet,
//   consumed by k_reduce, dead before k_filters writes. (Round-6 lesson:
//   appending past 8.39 MB overflowed ws and corrupted the harness's
//   pristine-input copy -> replay divergence.)
#define FXH_OFF 1024
#define ARR_ELEMS (B_*NOUT*W_)          // 1048576 ushorts = 2 MB each
#define PART_BOFF FXH_OFF               // overlay: float[32][768][5] = 491,520 B

typedef __bf16 bf16x8 __attribute__((ext_vector_type(8)));
typedef float f32x4 __attribute__((ext_vector_type(4)));

__device__ __forceinline__ unsigned short f2bf(float f) {
    unsigned int u = __float_as_uint(f);
    u = (u + 0x7FFFu + ((u >> 16) & 1u)) >> 16;
    return (unsigned short)u;
}
__device__ __forceinline__ float bf2f(unsigned short h) {
    return __uint_as_float(((unsigned int)h) << 16);
}
// 8 floats -> hi/lo bf16x8
__device__ __forceinline__ void cvt_hilo(const float* x, bf16x8* hi, bf16x8* lo) {
    union { unsigned int u[4]; bf16x8 v; } H, L;
    #pragma unroll
    for (int i = 0; i < 4; i++) {
        unsigned short h0 = f2bf(x[2*i]),  h1 = f2bf(x[2*i+1]);
        H.u[i] = (unsigned int)h0 | ((unsigned int)h1 << 16);
        unsigned short l0 = f2bf(x[2*i]   - bf2f(h0));
        unsigned short l1 = f2bf(x[2*i+1] - bf2f(h1));
        L.u[i] = (unsigned int)l0 | ((unsigned int)l1 << 16);
    }
    *hi = H.v; *lo = L.v;
}

// ---------------- kernel 1a: partials[b][chunk][j] = sum_{k in chunk} X[b,k] W[k,j] ----------------
// NO atomics (round-5 lesson: 768 cross-XCD RMWs per address serialize ~150us).
__global__ __launch_bounds__(256) void k_locnet(const float* __restrict__ X,
                                                const float* __restrict__ Wl,
                                                float* __restrict__ ws) {
    const int chunk = blockIdx.x;        // 0..767
    const int t = threadIdx.x;
    const size_t kbase = (size_t)chunk * LCE;

    __shared__ __align__(16) float Wlds[LCE * 5];   // 20 KB
    {
        const float4* Wg = (const float4*)(Wl + kbase * 5);
        #pragma unroll
        for (int i = 0; i < 5; i++)
            *(float4*)&Wlds[(t + 256 * i) * 4] = Wg[t + 256 * i];
    }
    __syncthreads();

    const int bb = t >> 3;   // 0..31
    const int j8 = t & 7;    // 0..7
    const float* Xr = X + (size_t)bb * FAN + kbase;

    float acc[5] = {};
    #pragma unroll 8
    for (int i = 0; i < 32; i++) {
        const int k0 = (j8 + 8 * i) * 4;
        float4 x = *(const float4*)(Xr + k0);
        const float* wr = &Wlds[k0 * 5];
        float xa[4] = {x.x, x.y, x.z, x.w};
        #pragma unroll
        for (int e = 0; e < 4; e++)
            #pragma unroll
            for (int jj = 0; jj < 5; jj++)
                acc[jj] += xa[e] * wr[e * 5 + jj];
    }

    #pragma unroll
    for (int off = 1; off < 8; off <<= 1)
        #pragma unroll
        for (int jj = 0; jj < 5; jj++)
            acc[jj] += __shfl_xor(acc[jj], off);

    if (j8 == 0) {
        float* pp = (float*)((char*)ws + PART_BOFF) + ((size_t)bb * LCHUNKS + chunk) * 5;
        #pragma unroll
        for (int jj = 0; jj < 5; jj++) pp[jj] = acc[jj];
    }
}

// ---------------- kernel 1b: p[b][j] = sum_chunk partials[b][chunk][j] ----------------
__global__ __launch_bounds__(256) void k_reduce(float* __restrict__ ws) {
    const int b = blockIdx.x;    // 0..31
    const int t = threadIdx.x;
    const float* base = (const float*)((char*)ws + PART_BOFF) + (size_t)b * LCHUNKS * 5;

    float acc[5] = {};
    #pragma unroll
    for (int i = 0; i < 3; i++) {
        int c = t + 256 * i;
        const float* pp = base + (size_t)c * 5;
        #pragma unroll
        for (int jj = 0; jj < 5; jj++) acc[jj] += pp[jj];
    }
    #pragma unroll
    for (int off = 32; off > 0; off >>= 1)
        #pragma unroll
        for (int jj = 0; jj < 5; jj++) acc[jj] += __shfl_down(acc[jj], off);

    __shared__ float sred[4][5];
    const int wave = t >> 6, lane = t & 63;
    if (lane == 0)
        #pragma unroll
        for (int jj = 0; jj < 5; jj++) sred[wave][jj] = acc[jj];
    __syncthreads();
    if (t < 5)
        ws[b * 5 + t] = sred[0][t] + sred[1][t] + sred[2][t] + sred[3][t];
}

// ---------------- kernel 2: filters -> bf16 hi/lo in ws ----------------
__global__ __launch_bounds__(256) void k_filters(const float* __restrict__ bl,
                                                 void* __restrict__ wsv) {
    const int n = blockIdx.x;      // 0..63
    const int b = blockIdx.y;      // 0..31
    const int which = blockIdx.z;  // 0: Fx, 1: Fy
    const int t = threadIdx.x;

    const float* pw = (const float*)wsv;
    unsigned short* arrh = (unsigned short*)((char*)wsv + FXH_OFF) + (size_t)which * 2 * ARR_ELEMS;
    unsigned short* arrl = arrh + ARR_ELEMS;

    const float p0 = pw[b * 5 + 0] + bl[0];
    const float p1 = pw[b * 5 + 1] + bl[1];
    const float p2 = pw[b * 5 + 2] + bl[2];
    const float p3 = pw[b * 5 + 3] + bl[3];

    const float g = (which == 0) ? 32.f * (p0 + 1.f) : 32.f * (p1 + 1.f);
    const float inv2s = 0.5f / expf(p2);
    const float delta = expf(p3) * (511.0f / 63.0f);
    const float mean = g + delta * ((float)n - 32.5f);

    float d0 = (float)t - mean;
    float f0 = expf(-d0 * d0 * inv2s);
    float d1 = (float)(t + 256) - mean;
    float f1 = expf(-d1 * d1 * inv2s);

    float s = f0 + f1;
    #pragma unroll
    for (int off = 32; off > 0; off >>= 1) s += __shfl_down(s, off);
    __shared__ float sred[4];
    __shared__ float stot;
    const int wave = t >> 6, lane = t & 63;
    if (lane == 0) sred[wave] = s;
    __syncthreads();
    if (t == 0) stot = sred[0] + sred[1] + sred[2] + sred[3] + 1e-4f;
    __syncthreads();
    const float scale = 1.0f / stot;

    const size_t o = ((size_t)b * NOUT + n) * W_;
    float v0 = f0 * scale, v1 = f1 * scale;
    unsigned short h0 = f2bf(v0), h1 = f2bf(v1);
    arrh[o + t] = h0;
    arrh[o + t + 256] = h1;
    arrl[o + t] = f2bf(v0 - bf2f(h0));
    arrl[o + t + 256] = f2bf(v1 - bf2f(h1));
}

// ---------------- kernel 3: MFMA glimpse, direct-fragment global loads ----------------
#define GP 72   // ushort pitch for G^T rows in LDS

__global__ __launch_bounds__(256) void k_glimpse(const float* __restrict__ X,
                                                 const float* __restrict__ bl,
                                                 const void* __restrict__ wsv,
                                                 float* __restrict__ out) {
    const int hc = blockIdx.x;   // 0..7
    const int bc = blockIdx.y;   // 0..95
    const int b = bc / 3;
    const int t = threadIdx.x;
    const int lane = t & 63;
    const int wv = t >> 6;       // 0..3
    const int l15 = lane & 15;
    const int quad = lane >> 4;  // 0..3
    const int hbase = hc * 64;

    const float* pw = (const float*)wsv;
    const unsigned short* fxh = (const unsigned short*)((const char*)wsv + FXH_OFF) + (size_t)b * NOUT * W_;
    const unsigned short* fxl = fxh + ARR_ELEMS;
    const unsigned short* fyh = fxh + 2 * ARR_ELEMS;
    const unsigned short* fyl = fxh + 3 * ARR_ELEMS;

    __shared__ __align__(16) unsigned short Gh[64 * GP];
    __shared__ __align__(16) unsigned short Gl[64 * GP];

    const float* Xp = X + (size_t)bc * (H_ * W_);

    // ---- GEMM1: barrier-free, frags straight from global ----
    f32x4 ahh[4] = {}, axl[4] = {};
    const size_t arow = (size_t)(hbase + 16 * wv + l15) * W_;
    #pragma unroll 4
    for (int ks = 0; ks < 16; ks++) {
        const int ko = ks * 32 + quad * 8;
        float xa[8];
        *(float4*)&xa[0] = *(const float4*)(Xp + arow + ko);
        *(float4*)&xa[4] = *(const float4*)(Xp + arow + ko + 4);
        bf16x8 ah, al;
        cvt_hilo(xa, &ah, &al);
        #pragma unroll
        for (int mt = 0; mt < 4; mt++) {
            const int fo = (16 * mt + l15) * W_ + ko;
            bf16x8 bh  = *(const bf16x8*)&fxh[fo];
            bf16x8 bl2 = *(const bf16x8*)&fxl[fo];
            ahh[mt] = __builtin_amdgcn_mfma_f32_16x16x32_bf16(ah, bh,  ahh[mt], 0, 0, 0);
            axl[mt] = __builtin_amdgcn_mfma_f32_16x16x32_bf16(al, bh,  axl[mt], 0, 0, 0);
            axl[mt] = __builtin_amdgcn_mfma_f32_16x16x32_bf16(ah, bl2, axl[mt], 0, 0, 0);
        }
    }

    // G^T -> LDS hi/lo
    #pragma unroll
    for (int mt = 0; mt < 4; mt++) {
        unsigned short gh[4], gl[4];
        #pragma unroll
        for (int r = 0; r < 4; r++) {
            float g = ahh[mt][r] + axl[mt][r];
            gh[r] = f2bf(g);
            gl[r] = f2bf(g - bf2f(gh[r]));
        }
        int o = (16 * mt + l15) * GP + 16 * wv + quad * 4;
        *(uint2*)&Gh[o] = make_uint2((unsigned int)gh[0] | ((unsigned int)gh[1] << 16),
                                     (unsigned int)gh[2] | ((unsigned int)gh[3] << 16));
        *(uint2*)&Gl[o] = make_uint2((unsigned int)gl[0] | ((unsigned int)gl[1] << 16),
                                     (unsigned int)gl[2] | ((unsigned int)gl[3] << 16));
    }
    __syncthreads();

    // ---- GEMM2: P[n][m] = sum_h Fy[n][hbase+h] * G[h][m] ----
    f32x4 ph[4] = {}, px[4] = {};
    const size_t yrow = (size_t)(16 * wv + l15) * W_ + hbase;
    #pragma unroll
    for (int ks = 0; ks < 2; ks++) {
        const int ko = ks * 32 + quad * 8;
        bf16x8 yh = *(const bf16x8*)&fyh[yrow + ko];
        bf16x8 yl = *(const bf16x8*)&fyl[yrow + ko];
        #pragma unroll
        for (int mt = 0; mt < 4; mt++) {
            const int go = (16 * mt + l15) * GP + ko;
            bf16x8 gh = *(const bf16x8*)&Gh[go];
            bf16x8 gl = *(const bf16x8*)&Gl[go];
            ph[mt] = __builtin_amdgcn_mfma_f32_16x16x32_bf16(yh, gh, ph[mt], 0, 0, 0);
            px[mt] = __builtin_amdgcn_mfma_f32_16x16x32_bf16(yl, gh, px[mt], 0, 0, 0);
            px[mt] = __builtin_amdgcn_mfma_f32_16x16x32_bf16(yh, gl, px[mt], 0, 0, 0);
        }
    }

    const float gamma = expf(pw[b * 5 + 4] + bl[4]);
    float* outp = out + (size_t)bc * (NOUT * NOUT);
    #pragma unroll
    for (int mt = 0; mt < 4; mt++)
        #pragma unroll
        for (int r = 0; r < 4; r++) {
            int n = 16 * wv + quad * 4 + r;
            int m = 16 * mt + l15;
            atomicAdd(&outp[n * NOUT + m], gamma * (ph[mt][r] + px[mt][r]));
        }
}

extern "C" void kernel_launch(void* const* d_in, const int* in_sizes, int n_in,
                              void* d_out, int out_size, void* d_ws, size_t ws_size,
                              hipStream_t stream) {
    const float* X  = (const float*)d_in[0];
    const float* Wl = (const float*)d_in[1];
    const float* bl = (const float*)d_in[2];
    float* out = (float*)d_out;
    float* ws  = (float*)d_ws;

    hipMemsetAsync(out, 0, (size_t)out_size * sizeof(float), stream);

    k_locnet<<<dim3(LCHUNKS), 256, 0, stream>>>(X, Wl, ws);
    k_reduce<<<dim3(B_), 256, 0, stream>>>(ws);
    k_filters<<<dim3(NOUT, B_, 2), 256, 0, stream>>>(bl, d_ws);
    k_glimpse<<<dim3(8, B_ * C_), 256, 0, stream>>>(X, bl, d_ws, out);
}